// Round 1
// 473.278 us; speedup vs baseline: 1.0710x; 1.0710x over previous
//
#include <hip/hip_runtime.h>

#define BB 16
#define SS 8192
#define DD 256

typedef __attribute__((ext_vector_type(8))) short bf16x8;
typedef __attribute__((ext_vector_type(4))) short bf16x4;
typedef __attribute__((ext_vector_type(4))) float f32x4;

union frag_u { bf16x8 v8; bf16x4 v4[2]; };

__device__ __forceinline__ unsigned short f2bf(float f) {
    union { float f; unsigned u; } v; v.f = f;
    unsigned r = v.u + 0x7FFFu + ((v.u >> 16) & 1u);   // round-to-nearest-even
    return (unsigned short)(r >> 16);
}
__device__ __forceinline__ unsigned pack2(float a, float b) {
    return (unsigned)f2bf(a) | ((unsigned)f2bf(b) << 16);
}
__device__ __forceinline__ bf16x8 ldfrag(const unsigned short* p) {
    frag_u f;
    f.v4[0] = *(const bf16x4*)(p);       // ds_read_b64
    f.v4[1] = *(const bf16x4*)(p + 4);   // ds_read_b64
    return f.v8;
}

#define LTS 40   // moment slab row stride in shorts: 80B, 16B-aligned rows -> b128 frag reads
#define ATS 36   // apply A-slab stride (legacy layout)

// ---------------------------------------------------------------------------
// moment: partial[kc][b][d][e] = sum_{s in kc-chunk} x[b,s,d]*x[b,s,e]  (bf16 MFMA)
// plus column sums (nh==0 blocks only). Grid (8 kc, 2 nh, 16 b) x 512 threads.
//
// v2 (latency fix): 8 waves/block (2/SIMD), block = 256m x 128n, one barrier per
// K-step via double-buffered LDS slab, global loads prefetched TWO steps ahead.
// Slab is plain Lt[d][s] (stride 80B): each thread loads 4 stride-64 d-columns
// (scalar b32, still 256B/instr coalesced) so staging writes are b64 at ~2x min
// aliasing and frag reads are single ds_read_b128 with 8 lanes/bank-quad = min
// (conflict-free). Kills the 9.4M SQ_LDS_BANK_CONFLICT of the prow layout.
// ---------------------------------------------------------------------------
__global__ __launch_bounds__(512) void moment_kernel(const float* __restrict__ x,
                                                     float* __restrict__ partial,
                                                     float* __restrict__ sumx) {
    const int kc = blockIdx.x;   // 0..7  : k-chunk of 1024 s-rows
    const int nh = blockIdx.y;   // 0..1  : which 128 output cols
    const int b  = blockIdx.z;
    const float* xb = x + ((size_t)b * SS + (size_t)kc * 1024) * DD;

    __shared__ unsigned short Lt0[256 * LTS];   // 20.0 KB
    __shared__ unsigned short Lt1[256 * LTS];   // 20.0 KB
    __shared__ float csh[8 * 256];              // 8 KB

    const int tid  = threadIdx.x;
    const int wave = tid >> 6;
    const int lane = tid & 63;
    const int lc   = lane & 15;
    const int lq   = lane >> 4;

    const int mrow0 = (wave & 3) * 64;              // 4 m-tiles of 16
    const int ncol0 = nh * 128 + (wave >> 2) * 64;  // 4 n-tiles of 16

    const int sg = tid >> 6;    // 0..7 : s-subrange (4 rows)
    const int dg = tid & 63;    // d-column base; owns d = dg + 64j
    const float* xt = xb + (size_t)(sg * 4) * DD + dg;

    f32x4 acc[4][4];
#pragma unroll
    for (int mi = 0; mi < 4; ++mi)
#pragma unroll
        for (int ni = 0; ni < 4; ++ni) acc[mi][ni] = (f32x4){0.f, 0.f, 0.f, 0.f};
    float cs[4] = {0.f, 0.f, 0.f, 0.f};

    float va[16], vb[16];   // v[i*4+j] = x[s0 + sg*4 + i][dg + 64j]

    auto LOAD = [&](float* v, int t) {
#pragma unroll
        for (int i = 0; i < 4; ++i)
#pragma unroll
            for (int j = 0; j < 4; ++j)
                v[i * 4 + j] = xt[(size_t)(t * 32 + i) * DD + 64 * j];
    };
    auto STAGE = [&](const float* v, unsigned short* Lw) {
        if (nh == 0) {
#pragma unroll
            for (int j = 0; j < 4; ++j)
                cs[j] += v[j] + v[4 + j] + v[8 + j] + v[12 + j];
        }
#pragma unroll
        for (int j = 0; j < 4; ++j) {
            uint2 w;
            w.x = pack2(v[j], v[4 + j]);
            w.y = pack2(v[8 + j], v[12 + j]);
            *(uint2*)&Lw[(dg + 64 * j) * LTS + sg * 4] = w;   // b64, 8B-aligned
        }
    };
    auto COMPUTE = [&](const unsigned short* Lr) {
        bf16x8 af[4], bfr[4];
#pragma unroll
        for (int mi = 0; mi < 4; ++mi)
            af[mi] = *(const bf16x8*)&Lr[(mrow0 + mi * 16 + lc) * LTS + lq * 8];
#pragma unroll
        for (int ni = 0; ni < 4; ++ni)
            bfr[ni] = *(const bf16x8*)&Lr[(ncol0 + ni * 16 + lc) * LTS + lq * 8];
#pragma unroll
        for (int mi = 0; mi < 4; ++mi)
#pragma unroll
            for (int ni = 0; ni < 4; ++ni)
                acc[mi][ni] = __builtin_amdgcn_mfma_f32_16x16x32_bf16(
                    af[mi], bfr[ni], acc[mi][ni], 0, 0, 0);
    };

    // prologue: step0 staged to Lt0; step1 loads in flight in vb
    LOAD(va, 0);
    STAGE(va, Lt0);
    LOAD(vb, 1);
    __syncthreads();

    for (int tt = 0; tt < 16; ++tt) {
        const int t0 = 2 * tt;
        // even step t0: read Lt0; stage step t0+1 (vb) -> Lt1; prefetch t0+2 -> va
        STAGE(vb, Lt1);                       // t0 <= 30, always stages
        if (t0 < 30) LOAD(va, t0 + 2);
        COMPUTE(Lt0);
        __syncthreads();
        // odd step t0+1: read Lt1; stage step t0+2 (va) -> Lt0; prefetch t0+3 -> vb
        if (t0 + 1 < 31) STAGE(va, Lt0);
        if (t0 + 1 < 30) LOAD(vb, t0 + 3);
        COMPUTE(Lt1);
        __syncthreads();
    }

    float* pp = partial + (size_t)(kc * 16 + b) * DD * DD;
#pragma unroll
    for (int mi = 0; mi < 4; ++mi)
#pragma unroll
        for (int ni = 0; ni < 4; ++ni) {
            const int row = mrow0 + mi * 16 + lq * 4;
            const int col = ncol0 + ni * 16 + lc;
#pragma unroll
            for (int r = 0; r < 4; ++r)
                pp[(size_t)(row + r) * DD + col] = acc[mi][ni][r];
        }

    if (nh == 0) {
        __syncthreads();
#pragma unroll
        for (int j = 0; j < 4; ++j) csh[sg * 256 + dg + 64 * j] = cs[j];
        __syncthreads();
        if (tid < 256) {
            float t0 = 0.f;
#pragma unroll
            for (int g = 0; g < 8; ++g) t0 += csh[g * 256 + tid];
            atomicAdd(&sumx[b * DD + tid], t0);
        }
    }
}

// ---------------------------------------------------------------------------
// stats: mean, trace(sigma), rsqrt(tr), 1/tr. trbuf: [0..15]=tr,[16..31]=rsqrt,[32..47]=1/tr
// ---------------------------------------------------------------------------
__global__ __launch_bounds__(256) void stats_kernel(const float* __restrict__ partial,
                                                    const float* __restrict__ sumx,
                                                    float* __restrict__ m,
                                                    float* __restrict__ trbuf) {
    const int b = blockIdx.x;
    const int d = threadIdx.x;
    const float mean = sumx[b * DD + d] * (1.0f / (float)SS);
    m[b * DD + d] = mean;
    float ds = 0.f;
#pragma unroll
    for (int kc = 0; kc < 8; ++kc)
        ds += partial[((size_t)(kc * 16 + b) * DD + d) * DD + d];
    const float diag = (ds - (float)SS * mean * mean) * (1.0f / (float)(SS - 1));
    __shared__ float red[256];
    red[d] = diag;
    __syncthreads();
    for (int off = 128; off > 0; off >>= 1) {
        if (d < off) red[d] += red[d + off];
        __syncthreads();
    }
    if (d == 0) {
        const float tr = red[0];
        trbuf[b]      = tr;
        trbuf[16 + b] = rsqrtf(tr);
        trbuf[32 + b] = 1.0f / tr;
    }
}

// ---------------------------------------------------------------------------
// sigman: Xa[b][d][e] = ((sum_kc partial - S*m_d*m_e)/(S-1)) / tr
// ---------------------------------------------------------------------------
__global__ __launch_bounds__(256) void sigman_kernel(const float* __restrict__ partial,
                                                     const float* __restrict__ m,
                                                     const float* __restrict__ trbuf,
                                                     float* __restrict__ Xa) {
    const int b = blockIdx.y;
    const int d = blockIdx.x;
    const int e = threadIdx.x;
    const float itr = trbuf[32 + b];
    const float md = m[b * DD + d];
    const float me = m[b * DD + e];
    float s = 0.f;
#pragma unroll
    for (int kc = 0; kc < 8; ++kc)
        s += partial[((size_t)(kc * 16 + b) * DD + d) * DD + e];
    Xa[(size_t)b * DD * DD + (size_t)d * DD + e] =
        (s - (float)SS * md * me) * (1.0f / (float)(SS - 1)) * itr;
}

// ---------------------------------------------------------------------------
// Batched 256^3 fp32 matmul (NS iterates are symmetric polys of sigma_n; A staged
// k-major via symmetry). op==1 applies W = 1.5*I - 0.5*X at load.
// ---------------------------------------------------------------------------
template <int TA, int TB>
__global__ __launch_bounds__(256) void bmm_ns(const float* __restrict__ A,
                                              const float* __restrict__ B,
                                              float* __restrict__ C) {
    const int b  = blockIdx.y;
    const int m0 = (blockIdx.x >> 2) * 64;
    const int n0 = (blockIdx.x & 3) * 64;
    const float* Ab = A + (size_t)b * DD * DD;
    const float* Bb = B + (size_t)b * DD * DD;

    __shared__ float As[64][64];
    __shared__ float Bsh[64][64];

    const int tid  = threadIdx.x;
    const int ty   = tid >> 4;
    const int tx   = tid & 15;
    const int lrow = tid >> 4;
    const int lcol = (tid & 15) * 4;

    float acc[4][4];
#pragma unroll
    for (int i = 0; i < 4; ++i)
#pragma unroll
        for (int j = 0; j < 4; ++j) acc[i][j] = 0.0f;

    for (int k0 = 0; k0 < DD; k0 += 64) {
#pragma unroll
        for (int t = 0; t < 4; ++t) {
            const int row = lrow + t * 16;
            float4 va = *(const float4*)&Ab[(size_t)(k0 + row) * DD + m0 + lcol];
            if (TA == 1) {
                const int gk = k0 + row, gm = m0 + lcol;
                va.x = ((gk == gm + 0) ? 1.5f : 0.0f) - 0.5f * va.x;
                va.y = ((gk == gm + 1) ? 1.5f : 0.0f) - 0.5f * va.y;
                va.z = ((gk == gm + 2) ? 1.5f : 0.0f) - 0.5f * va.z;
                va.w = ((gk == gm + 3) ? 1.5f : 0.0f) - 0.5f * va.w;
            }
            *(float4*)&As[row][lcol] = va;

            float4 vb = *(const float4*)&Bb[(size_t)(k0 + row) * DD + n0 + lcol];
            if (TB == 1) {
                const int gk = k0 + row, gn = n0 + lcol;
                vb.x = ((gk == gn + 0) ? 1.5f : 0.0f) - 0.5f * vb.x;
                vb.y = ((gk == gn + 1) ? 1.5f : 0.0f) - 0.5f * vb.y;
                vb.z = ((gk == gn + 2) ? 1.5f : 0.0f) - 0.5f * vb.z;
                vb.w = ((gk == gn + 3) ? 1.5f : 0.0f) - 0.5f * vb.w;
            }
            *(float4*)&Bsh[row][lcol] = vb;
        }
        __syncthreads();
#pragma unroll 8
        for (int kk = 0; kk < 64; ++kk) {
            const float4 av = *(const float4*)&As[kk][ty * 4];
            const float4 bv = *(const float4*)&Bsh[kk][tx * 4];
            const float a4[4] = {av.x, av.y, av.z, av.w};
            const float b4[4] = {bv.x, bv.y, bv.z, bv.w};
#pragma unroll
            for (int i = 0; i < 4; ++i)
#pragma unroll
                for (int j = 0; j < 4; ++j) acc[i][j] += a4[i] * b4[j];
        }
        __syncthreads();
    }

    float* Cb = C + (size_t)b * DD * DD;
#pragma unroll
    for (int i = 0; i < 4; ++i) {
        float4 vv = make_float4(acc[i][0], acc[i][1], acc[i][2], acc[i][3]);
        *(float4*)&Cb[(size_t)(m0 + ty * 4 + i) * DD + n0 + tx * 4] = vv;
    }
}

// ---------------------------------------------------------------------------
// apply: out[b,s,e] = sum_d (x[b,s,d]-m[b,d]) * wm[b,d,e],  wm = P*rsqrt(tr).
// bf16 MFMA. wm symmetric -> B fragment reads wm rows (k-contiguous, no transpose).
// Grid (64 s-tiles, 2 n-halves, 16 b) x 256 thr; 128x128 tile, K=256.
// B-slab (128 n-rows x 256 k, bf16, +4 pad) staged once; A per k-step of 32.
// ---------------------------------------------------------------------------
#define BSS 260
__global__ __launch_bounds__(256) void apply_kernel(const float* __restrict__ x,
                                                    const float* __restrict__ P,
                                                    const float* __restrict__ m,
                                                    const float* __restrict__ trbuf,
                                                    float* __restrict__ out) {
    const int st = blockIdx.x;
    const int nh = blockIdx.y;
    const int b  = blockIdx.z;
    const int s0 = st * 128;
    const int n0 = nh * 128;
    const float rs = trbuf[16 + b];
    const float* xb = x + (size_t)b * SS * DD;
    const float* Pb = P + (size_t)b * DD * DD;
    const float* mb = m + b * DD;
    float* ob = out + (size_t)b * SS * DD;

    __shared__ unsigned short Bs[128 * BSS];   // 66.6 KB
    __shared__ unsigned short As[128 * ATS];   // 9.2 KB

    const int tid  = threadIdx.x;
    const int wave = tid >> 6;
    const int lane = tid & 63;
    const int lc = lane & 15, lq = lane >> 4;
    const int mrow0 = (wave & 1) * 64;
    const int ncol0 = (wave >> 1) * 64;

    {   // stage B once (rs folded in); wm[k][n]=wm[n][k] by symmetry
        const int r = tid >> 1, h = tid & 1;
        const float* prow = Pb + (size_t)(n0 + r) * DD + h * 128;
        unsigned short* brow = &Bs[r * BSS + h * 128];
#pragma unroll
        for (int i = 0; i < 32; ++i) {
            float4 pv = *(const float4*)(prow + i * 4);
            *(unsigned*)&brow[i * 4]     = pack2(pv.x * rs, pv.y * rs);
            *(unsigned*)&brow[i * 4 + 2] = pack2(pv.z * rs, pv.w * rs);
        }
    }
    __syncthreads();

    f32x4 acc[4][4];
#pragma unroll
    for (int mi = 0; mi < 4; ++mi)
#pragma unroll
        for (int ni = 0; ni < 4; ++ni) acc[mi][ni] = (f32x4){0.f, 0.f, 0.f, 0.f};

    const int r8 = tid >> 3;          // 0..31
    const int d4 = (tid & 7) * 4;

    for (int k0 = 0; k0 < DD; k0 += 32) {
        float4 vv[4];
        const float4 mm = *(const float4*)(mb + k0 + d4);
#pragma unroll
        for (int i = 0; i < 4; ++i) {
            const int r = r8 + i * 32;
            float4 t = *(const float4*)(xb + (size_t)(s0 + r) * DD + k0 + d4);
            t.x -= mm.x; t.y -= mm.y; t.z -= mm.z; t.w -= mm.w;
            vv[i] = t;
        }
        __syncthreads();   // previous step's A-frag reads done
#pragma unroll
        for (int i = 0; i < 4; ++i) {
            unsigned short* arow = &As[(r8 + i * 32) * ATS + d4];
            *(unsigned*)&arow[0] = pack2(vv[i].x, vv[i].y);
            *(unsigned*)&arow[2] = pack2(vv[i].z, vv[i].w);
        }
        __syncthreads();

        bf16x8 af[4], bfr[4];
#pragma unroll
        for (int mi = 0; mi < 4; ++mi)
            af[mi] = ldfrag(&As[(mrow0 + mi * 16 + lc) * ATS + lq * 8]);
#pragma unroll
        for (int ni = 0; ni < 4; ++ni)
            bfr[ni] = ldfrag(&Bs[(ncol0 + ni * 16 + lc) * BSS + k0 + lq * 8]);
#pragma unroll
        for (int mi = 0; mi < 4; ++mi)
#pragma unroll
            for (int ni = 0; ni < 4; ++ni)
                acc[mi][ni] = __builtin_amdgcn_mfma_f32_16x16x32_bf16(
                    af[mi], bfr[ni], acc[mi][ni], 0, 0, 0);
    }

#pragma unroll
    for (int mi = 0; mi < 4; ++mi)
#pragma unroll
        for (int ni = 0; ni < 4; ++ni) {
            const int row = s0 + mrow0 + mi * 16 + lq * 4;
            const int col = n0 + ncol0 + ni * 16 + lc;
#pragma unroll
            for (int r = 0; r < 4; ++r)
                ob[(size_t)(row + r) * DD + col] = acc[mi][ni][r];
        }
}

extern "C" void kernel_launch(void* const* d_in, const int* in_sizes, int n_in,
                              void* d_out, int out_size, void* d_ws, size_t ws_size,
                              hipStream_t stream) {
    const float* x = (const float*)d_in[0];
    float* out = (float*)d_out;
    float* ws = (float*)d_ws;

    const size_t MAT = (size_t)BB * DD * DD;        // 1,048,576 floats
    float* partial = ws;                            // 8 * MAT = 32 MB
    float* sumx  = partial + 8 * MAT;               // 4096
    float* m     = sumx + BB * DD;                  // 4096
    float* trbuf = m + BB * DD;                     // 64
    float* Xa    = trbuf + 64;
    float* Xb    = Xa + MAT;
    float* T     = Xb + MAT;
    float* Pa    = T + MAT;
    float* Pb    = Pa + MAT;
    // total ~54.6 MB of workspace

    hipMemsetAsync(sumx, 0, (size_t)BB * DD * sizeof(float), stream);

    moment_kernel<<<dim3(8, 2, 16), 512, 0, stream>>>(x, partial, sumx);
    stats_kernel<<<16, 256, 0, stream>>>(partial, sumx, m, trbuf);
    sigman_kernel<<<dim3(256, 16), 256, 0, stream>>>(partial, m, trbuf, Xa);

    // Newton-Schulz, commutative form: X0 = sigma_n (in Xa), P1 = W0 (implicit)
    bmm_ns<1, 1><<<dim3(16, 16), 256, 0, stream>>>(Xa, Xa, T);   // T  = W0^2
    bmm_ns<0, 0><<<dim3(16, 16), 256, 0, stream>>>(Xa, T, Xb);   // X1 = X0*W0^2
    bmm_ns<1, 1><<<dim3(16, 16), 256, 0, stream>>>(Xa, Xb, Pa);  // P2 = W0*W1
    bmm_ns<1, 1><<<dim3(16, 16), 256, 0, stream>>>(Xb, Xb, T);   // T  = W1^2
    bmm_ns<0, 0><<<dim3(16, 16), 256, 0, stream>>>(Xb, T, Xa);   // X2 = X1*W1^2
    bmm_ns<0, 1><<<dim3(16, 16), 256, 0, stream>>>(Pa, Xa, Pb);  // P3 = P2*W2
    bmm_ns<1, 1><<<dim3(16, 16), 256, 0, stream>>>(Xa, Xa, T);   // T  = W2^2
    bmm_ns<0, 0><<<dim3(16, 16), 256, 0, stream>>>(Xa, T, Xb);   // X3 = X2*W2^2
    bmm_ns<0, 1><<<dim3(16, 16), 256, 0, stream>>>(Pb, Xb, Pa);  // P4 = P3*W3

    apply_kernel<<<dim3(64, 2, 16), 512 / 2, 0, stream>>>(x, Pa, m, trbuf, out);
}

// Round 3
// 372.832 us; speedup vs baseline: 1.3596x; 1.2694x over previous
//
#include <hip/hip_runtime.h>

#define BB 16
#define SS 8192
#define DD 256

typedef __attribute__((ext_vector_type(8))) short bf16x8;
typedef __attribute__((ext_vector_type(4))) short bf16x4;
typedef __attribute__((ext_vector_type(4))) float f32x4;

union frag_u { bf16x8 v8; bf16x4 v4[2]; };

__device__ __forceinline__ unsigned short f2bf(float f) {
    union { float f; unsigned u; } v; v.f = f;
    unsigned r = v.u + 0x7FFFu + ((v.u >> 16) & 1u);   // round-to-nearest-even
    return (unsigned short)(r >> 16);
}
__device__ __forceinline__ float bf2f(unsigned short u) {
    union { unsigned u; float f; } cv; cv.u = (unsigned)u << 16; return cv.f;
}
__device__ __forceinline__ unsigned pack2(float a, float b) {
    return (unsigned)f2bf(a) | ((unsigned)f2bf(b) << 16);
}
__device__ __forceinline__ bf16x8 ldfrag(const unsigned short* p) {
    frag_u f;
    f.v4[0] = *(const bf16x4*)(p);       // ds_read_b64
    f.v4[1] = *(const bf16x4*)(p + 4);   // ds_read_b64
    return f.v8;
}
// split w into hi+lo bf16 (residual ~2^-18 relative)
__device__ __forceinline__ void split_bf(float w, unsigned short& hi, unsigned short& lo) {
    hi = f2bf(w);
    lo = f2bf(w - bf2f(hi));
}

#define LTS 40   // slab row stride in shorts: 80B, 16B-aligned rows -> b128 frag reads

// ---------------------------------------------------------------------------
// moment: partial[kc][b][d][e] = sum_{s in kc-chunk} x[b,s,d]*x[b,s,e]  (bf16 MFMA)
// plus per-(kc,b) column sums written non-atomically to sumx8 (no memset needed).
// Grid (8 kc, 2 nh, 16 b) x 512 threads. 8 waves, double-buffered LDS slab,
// register prefetch 2 steps ahead, one barrier per K-step.
// ---------------------------------------------------------------------------
__global__ __launch_bounds__(512) void moment_kernel(const float* __restrict__ x,
                                                     float* __restrict__ partial,
                                                     float* __restrict__ sumx8) {
    const int kc = blockIdx.x;   // 0..7  : k-chunk of 1024 s-rows
    const int nh = blockIdx.y;   // 0..1  : which 128 output cols
    const int b  = blockIdx.z;
    const float* xb = x + ((size_t)b * SS + (size_t)kc * 1024) * DD;

    __shared__ unsigned short Lt0[256 * LTS];   // 20.0 KB
    __shared__ unsigned short Lt1[256 * LTS];   // 20.0 KB
    __shared__ float csh[8 * 256];              // 8 KB

    const int tid  = threadIdx.x;
    const int wave = tid >> 6;
    const int lane = tid & 63;
    const int lc   = lane & 15;
    const int lq   = lane >> 4;

    const int mrow0 = (wave & 3) * 64;              // 4 m-tiles of 16
    const int ncol0 = nh * 128 + (wave >> 2) * 64;  // 4 n-tiles of 16

    const int sg = tid >> 6;    // 0..7 : s-subrange (4 rows)
    const int dg = tid & 63;    // d-column base; owns d = dg + 64j
    const float* xt = xb + (size_t)(sg * 4) * DD + dg;

    f32x4 acc[4][4];
#pragma unroll
    for (int mi = 0; mi < 4; ++mi)
#pragma unroll
        for (int ni = 0; ni < 4; ++ni) acc[mi][ni] = (f32x4){0.f, 0.f, 0.f, 0.f};
    float cs[4] = {0.f, 0.f, 0.f, 0.f};

    float va[16], vb[16];   // v[i*4+j] = x[s0 + sg*4 + i][dg + 64j]

    auto LOAD = [&](float* v, int t) {
#pragma unroll
        for (int i = 0; i < 4; ++i)
#pragma unroll
            for (int j = 0; j < 4; ++j)
                v[i * 4 + j] = xt[(size_t)(t * 32 + i) * DD + 64 * j];
    };
    auto STAGE = [&](const float* v, unsigned short* Lw) {
        if (nh == 0) {
#pragma unroll
            for (int j = 0; j < 4; ++j)
                cs[j] += v[j] + v[4 + j] + v[8 + j] + v[12 + j];
        }
#pragma unroll
        for (int j = 0; j < 4; ++j) {
            uint2 w;
            w.x = pack2(v[j], v[4 + j]);
            w.y = pack2(v[8 + j], v[12 + j]);
            *(uint2*)&Lw[(dg + 64 * j) * LTS + sg * 4] = w;   // b64, 8B-aligned
        }
    };
    auto COMPUTE = [&](const unsigned short* Lr) {
        bf16x8 af[4], bfr[4];
#pragma unroll
        for (int mi = 0; mi < 4; ++mi)
            af[mi] = *(const bf16x8*)&Lr[(mrow0 + mi * 16 + lc) * LTS + lq * 8];
#pragma unroll
        for (int ni = 0; ni < 4; ++ni)
            bfr[ni] = *(const bf16x8*)&Lr[(ncol0 + ni * 16 + lc) * LTS + lq * 8];
#pragma unroll
        for (int mi = 0; mi < 4; ++mi)
#pragma unroll
            for (int ni = 0; ni < 4; ++ni)
                acc[mi][ni] = __builtin_amdgcn_mfma_f32_16x16x32_bf16(
                    af[mi], bfr[ni], acc[mi][ni], 0, 0, 0);
    };

    // prologue: step0 staged to Lt0; step1 loads in flight in vb
    LOAD(va, 0);
    STAGE(va, Lt0);
    LOAD(vb, 1);
    __syncthreads();

    for (int tt = 0; tt < 16; ++tt) {
        const int t0 = 2 * tt;
        STAGE(vb, Lt1);                       // stage step t0+1
        if (t0 < 30) LOAD(va, t0 + 2);
        COMPUTE(Lt0);
        __syncthreads();
        if (t0 + 1 < 31) STAGE(va, Lt0);      // stage step t0+2
        if (t0 + 1 < 30) LOAD(vb, t0 + 3);
        COMPUTE(Lt1);
        __syncthreads();
    }

    float* pp = partial + (size_t)(kc * 16 + b) * DD * DD;
#pragma unroll
    for (int mi = 0; mi < 4; ++mi)
#pragma unroll
        for (int ni = 0; ni < 4; ++ni) {
            const int row = mrow0 + mi * 16 + lq * 4;
            const int col = ncol0 + ni * 16 + lc;
#pragma unroll
            for (int r = 0; r < 4; ++r)
                pp[(size_t)(row + r) * DD + col] = acc[mi][ni][r];
        }

    if (nh == 0) {
        __syncthreads();
#pragma unroll
        for (int j = 0; j < 4; ++j) csh[sg * 256 + dg + 64 * j] = cs[j];
        __syncthreads();
        if (tid < 256) {
            float t0 = 0.f;
#pragma unroll
            for (int g = 0; g < 8; ++g) t0 += csh[g * 256 + tid];
            sumx8[(size_t)(kc * 16 + b) * DD + tid] = t0;   // non-atomic slot
        }
    }
}

// ---------------------------------------------------------------------------
// stats: mean (from sumx8 slots), trace(sigma), rsqrt(tr), 1/tr.
// trbuf: [0..15]=tr, [16..31]=rsqrt, [32..47]=1/tr
// ---------------------------------------------------------------------------
__global__ __launch_bounds__(256) void stats_kernel(const float* __restrict__ partial,
                                                    const float* __restrict__ sumx8,
                                                    float* __restrict__ m,
                                                    float* __restrict__ trbuf) {
    const int b = blockIdx.x;
    const int d = threadIdx.x;
    float sx = 0.f;
#pragma unroll
    for (int kc = 0; kc < 8; ++kc)
        sx += sumx8[(size_t)(kc * 16 + b) * DD + d];
    const float mean = sx * (1.0f / (float)SS);
    m[b * DD + d] = mean;
    float ds = 0.f;
#pragma unroll
    for (int kc = 0; kc < 8; ++kc)
        ds += partial[((size_t)(kc * 16 + b) * DD + d) * DD + d];
    const float diag = (ds - (float)SS * mean * mean) * (1.0f / (float)(SS - 1));
    __shared__ float red[256];
    red[d] = diag;
    __syncthreads();
    for (int off = 128; off > 0; off >>= 1) {
        if (d < off) red[d] += red[d + off];
        __syncthreads();
    }
    if (d == 0) {
        const float tr = red[0];
        trbuf[b]      = tr;
        trbuf[16 + b] = rsqrtf(tr);
        trbuf[32 + b] = 1.0f / tr;
    }
}

// ---------------------------------------------------------------------------
// sigman: Xa[b][d][e] = ((sum_kc partial - S*m_d*m_e)/(S-1)) / tr
// ---------------------------------------------------------------------------
__global__ __launch_bounds__(256) void sigman_kernel(const float* __restrict__ partial,
                                                     const float* __restrict__ m,
                                                     const float* __restrict__ trbuf,
                                                     float* __restrict__ Xa) {
    const int b = blockIdx.y;
    const int d = blockIdx.x;
    const int e = threadIdx.x;
    const float itr = trbuf[32 + b];
    const float md = m[b * DD + d];
    const float me = m[b * DD + e];
    float s = 0.f;
#pragma unroll
    for (int kc = 0; kc < 8; ++kc)
        s += partial[((size_t)(kc * 16 + b) * DD + d) * DD + e];
    Xa[(size_t)b * DD * DD + (size_t)d * DD + e] =
        (s - (float)SS * md * me) * (1.0f / (float)(SS - 1)) * itr;
}

// ---------------------------------------------------------------------------
// Batched 256^3 matmul via MFMA with split-bf16 (hi+lo) fp32 emulation:
// C = opA(A) @ opB(B), op = identity or W(X) = 1.5I - 0.5X (runtime flag).
// All operands are symmetric (polynomials of sigma_n) -> both slabs load
// k-contiguous rows directly. 64x64 tile, 4 waves of 32x32, K-chunks of 64,
// double-buffered LDS, register prefetch, one barrier per chunk.
// Two independent batch-sets per launch (set = blockIdx.y>>4) to fuse
// independent NS products into one dispatch.
// ---------------------------------------------------------------------------
#define BTS 72   // bmm slab stride in shorts: 144B = 9 quads -> conflict-free b128
__global__ __launch_bounds__(256) void bmm_mfma(
    const float* __restrict__ A0, const float* __restrict__ B0, float* __restrict__ C0,
    int ta0, int tb0,
    const float* __restrict__ A1, const float* __restrict__ B1, float* __restrict__ C1,
    int ta1, int tb1) {
    const int by  = blockIdx.y;
    const int set = by >> 4;
    const int bb  = by & 15;
    const float* Ag = (set ? A1 : A0) + (size_t)bb * DD * DD;
    const float* Bg = (set ? B1 : B0) + (size_t)bb * DD * DD;
    float*       Cg = (set ? C1 : C0) + (size_t)bb * DD * DD;
    const int TA = set ? ta1 : ta0;
    const int TB = set ? tb1 : tb0;

    const int m0 = (blockIdx.x >> 2) * 64;
    const int n0 = (blockIdx.x & 3) * 64;

    __shared__ unsigned short Ahi[2][64 * BTS];   // 4 slabs x 2 bufs = 72 KB total
    __shared__ unsigned short Alo[2][64 * BTS];
    __shared__ unsigned short Bhi[2][64 * BTS];
    __shared__ unsigned short Blo[2][64 * BTS];

    const int tid  = threadIdx.x;
    const int wave = tid >> 6;
    const int lane = tid & 63;
    const int lc = lane & 15, lq = lane >> 4;
    const int mrow0 = (wave & 1) * 32;
    const int ncol0 = (wave >> 1) * 32;

    const int r  = tid >> 2;          // 0..63 : slab row
    const int kl = (tid & 3) * 4;     // k offset within 16-float group
    const float* Arow = Ag + (size_t)(m0 + r) * DD + kl;
    const float* Brow = Bg + (size_t)(n0 + r) * DD + kl;

    f32x4 acc[2][2];
#pragma unroll
    for (int mi = 0; mi < 2; ++mi)
#pragma unroll
        for (int ni = 0; ni < 2; ++ni) acc[mi][ni] = (f32x4){0.f, 0.f, 0.f, 0.f};

    float4 va0[4], vb0[4], va1[4], vb1[4];

    auto LOADC = [&](float4* va, float4* vb, int c) {
#pragma unroll
        for (int i = 0; i < 4; ++i) va[i] = *(const float4*)(Arow + c * 64 + i * 16);
#pragma unroll
        for (int i = 0; i < 4; ++i) vb[i] = *(const float4*)(Brow + c * 64 + i * 16);
    };
    auto STAGE_SIDE = [&](const float4* v, unsigned short* Shi, unsigned short* Slo,
                          int c, int gmn, int tflag) {
#pragma unroll
        for (int i = 0; i < 4; ++i) {
            float xv[4] = {v[i].x, v[i].y, v[i].z, v[i].w};
            unsigned short h[4], l[4];
#pragma unroll
            for (int j = 0; j < 4; ++j) {
                float wv = xv[j];
                if (tflag) {
                    const int gk = c * 64 + kl + i * 16 + j;
                    wv = ((gk == gmn) ? 1.5f : 0.0f) - 0.5f * wv;
                }
                split_bf(wv, h[j], l[j]);
            }
            unsigned short* ph = &Shi[r * BTS + kl + i * 16];
            *(unsigned*)&ph[0] = (unsigned)h[0] | ((unsigned)h[1] << 16);
            *(unsigned*)&ph[2] = (unsigned)h[2] | ((unsigned)h[3] << 16);
            unsigned short* pl = &Slo[r * BTS + kl + i * 16];
            *(unsigned*)&pl[0] = (unsigned)l[0] | ((unsigned)l[1] << 16);
            *(unsigned*)&pl[2] = (unsigned)l[2] | ((unsigned)l[3] << 16);
        }
    };
    auto STAGE = [&](const float4* va, const float4* vb, int c, int buf) {
        STAGE_SIDE(va, Ahi[buf], Alo[buf], c, m0 + r, TA);
        STAGE_SIDE(vb, Bhi[buf], Blo[buf], c, n0 + r, TB);
    };
    auto COMPUTE = [&](int buf) {
#pragma unroll
        for (int ks = 0; ks < 2; ++ks) {
            bf16x8 ah[2], al[2], bh[2], bl[2];
#pragma unroll
            for (int mi = 0; mi < 2; ++mi) {
                const int off = (mrow0 + mi * 16 + lc) * BTS + ks * 32 + lq * 8;
                ah[mi] = *(const bf16x8*)&Ahi[buf][off];
                al[mi] = *(const bf16x8*)&Alo[buf][off];
            }
#pragma unroll
            for (int ni = 0; ni < 2; ++ni) {
                const int off = (ncol0 + ni * 16 + lc) * BTS + ks * 32 + lq * 8;
                bh[ni] = *(const bf16x8*)&Bhi[buf][off];
                bl[ni] = *(const bf16x8*)&Blo[buf][off];
            }
#pragma unroll
            for (int mi = 0; mi < 2; ++mi)
#pragma unroll
                for (int ni = 0; ni < 2; ++ni) {
                    acc[mi][ni] = __builtin_amdgcn_mfma_f32_16x16x32_bf16(
                        al[mi], bh[ni], acc[mi][ni], 0, 0, 0);
                    acc[mi][ni] = __builtin_amdgcn_mfma_f32_16x16x32_bf16(
                        ah[mi], bl[ni], acc[mi][ni], 0, 0, 0);
                    acc[mi][ni] = __builtin_amdgcn_mfma_f32_16x16x32_bf16(
                        ah[mi], bh[ni], acc[mi][ni], 0, 0, 0);
                }
        }
    };

    // 4 K-chunks of 64, double-buffered, prefetch 2 ahead
    LOADC(va0, vb0, 0);
    STAGE(va0, vb0, 0, 0);
    LOADC(va1, vb1, 1);
    __syncthreads();
#pragma unroll
    for (int cc = 0; cc < 2; ++cc) {
        const int c0 = 2 * cc;
        STAGE(va1, vb1, c0 + 1, 1);
        if (c0 + 2 < 4) LOADC(va0, vb0, c0 + 2);
        COMPUTE(0);
        __syncthreads();
        if (c0 + 2 < 4) STAGE(va0, vb0, c0 + 2, 0);
        if (c0 + 3 < 4) LOADC(va1, vb1, c0 + 3);
        COMPUTE(1);
        __syncthreads();
    }

#pragma unroll
    for (int mi = 0; mi < 2; ++mi)
#pragma unroll
        for (int ni = 0; ni < 2; ++ni) {
            const int row = m0 + mrow0 + mi * 16 + lq * 4;
            const int col = n0 + ncol0 + ni * 16 + lc;
#pragma unroll
            for (int rr = 0; rr < 4; ++rr)
                Cg[(size_t)(row + rr) * DD + col] = acc[mi][ni][rr];
        }
}

// ---------------------------------------------------------------------------
// apply: out[b,s,e] = sum_d x[b,s,d]*wm[d,e] - corr[e],  corr[e]=sum_d m[d]*wm[d,e],
// wm = P*rsqrt(tr) (bf16, rs folded at stage). Grid (32 st, 2 nh, 16 b) x 512.
// 256x128 tile; 8 waves, each 64x64 (acc[4][4] -- the round-2 bug was acc[4][2],
// leaving half the columns unwritten). B-slab staged once; A-slab double-buffered,
// register prefetch 2 K-steps ahead, one barrier per K-step.
// ---------------------------------------------------------------------------
#define BSS 260
__global__ __launch_bounds__(512) void apply_kernel(const float* __restrict__ x,
                                                    const float* __restrict__ P,
                                                    const float* __restrict__ m,
                                                    const float* __restrict__ trbuf,
                                                    float* __restrict__ out) {
    const int st = blockIdx.x;
    const int nh = blockIdx.y;
    const int b  = blockIdx.z;
    const int s0 = st * 256;
    const int n0 = nh * 128;
    const float rs = trbuf[16 + b];
    const float* xb = x + (size_t)b * SS * DD;
    const float* Pb = P + (size_t)b * DD * DD;
    const float* mb = m + b * DD;
    float* ob = out + (size_t)b * SS * DD;

    __shared__ unsigned short Bs[128 * BSS];    // 66.6 KB
    __shared__ unsigned short As0[256 * LTS];   // 20 KB
    __shared__ unsigned short As1[256 * LTS];   // 20 KB
    __shared__ float corr[128];

    const int tid  = threadIdx.x;
    const int wave = tid >> 6;
    const int lane = tid & 63;
    const int lc = lane & 15, lq = lane >> 4;
    const int mrow0 = (wave & 3) * 64;   // 4 m-groups of 64
    const int ncol0 = (wave >> 2) * 64;  // 2 n-groups of 64

    {   // stage B once (rs folded in); wm[k][n]=wm[n][k] by symmetry
        const int r = tid >> 2, h = tid & 3;
        const float* prow = Pb + (size_t)(n0 + r) * DD + h * 64;
        unsigned short* brow = &Bs[r * BSS + h * 64];
#pragma unroll
        for (int i = 0; i < 16; ++i) {
            float4 pv = *(const float4*)(prow + i * 4);
            *(unsigned*)&brow[i * 4]     = pack2(pv.x * rs, pv.y * rs);
            *(unsigned*)&brow[i * 4 + 2] = pack2(pv.z * rs, pv.w * rs);
        }
    }
    __syncthreads();

    // rank-1 mean correction: corr[n] = sum_k m[k] * wm[k][n]  (from bf16 slab)
    if (tid < 128) {
        float s = 0.f;
        for (int k = 0; k < 256; ++k)
            s += mb[k] * bf2f(Bs[tid * BSS + k]);
        corr[tid] = s;
    }

    f32x4 acc[4][4];
#pragma unroll
    for (int mi = 0; mi < 4; ++mi)
#pragma unroll
        for (int ni = 0; ni < 4; ++ni) acc[mi][ni] = (f32x4){0.f, 0.f, 0.f, 0.f};

    const int r8 = tid >> 3;          // 0..63
    const int d4 = (tid & 7) * 4;     // k offset 0..28
    const float* xt = xb + (size_t)(s0 + r8) * DD + d4;

    float4 va[4], vb[4];

    auto LOAD = [&](float4* v, int t) {
#pragma unroll
        for (int i = 0; i < 4; ++i)
            v[i] = *(const float4*)(xt + (size_t)t * 32 + (size_t)i * 64 * DD);
    };
    auto STAGE = [&](const float4* v, unsigned short* Aw) {
#pragma unroll
        for (int i = 0; i < 4; ++i) {
            uint2 w;
            w.x = pack2(v[i].x, v[i].y);
            w.y = pack2(v[i].z, v[i].w);
            *(uint2*)&Aw[(r8 + i * 64) * LTS + d4] = w;
        }
    };
    auto COMPUTE = [&](const unsigned short* Ar, int t) {
        const int k0 = t * 32;
        bf16x8 af[4], bfr[4];
#pragma unroll
        for (int mi = 0; mi < 4; ++mi)
            af[mi] = *(const bf16x8*)&Ar[(mrow0 + mi * 16 + lc) * LTS + lq * 8];
#pragma unroll
        for (int ni = 0; ni < 4; ++ni)
            bfr[ni] = ldfrag(&Bs[(ncol0 + ni * 16 + lc) * BSS + k0 + lq * 8]);
#pragma unroll
        for (int mi = 0; mi < 4; ++mi)
#pragma unroll
            for (int ni = 0; ni < 4; ++ni)
                acc[mi][ni] = __builtin_amdgcn_mfma_f32_16x16x32_bf16(
                    af[mi], bfr[ni], acc[mi][ni], 0, 0, 0);
    };

    // K = 256 in 8 steps of 32; double-buffered A, prefetch 2 ahead
    LOAD(va, 0);
    STAGE(va, As0);
    LOAD(vb, 1);
    __syncthreads();

#pragma unroll
    for (int tt = 0; tt < 4; ++tt) {
        const int t0 = 2 * tt;
        STAGE(vb, As1);                      // stage step t0+1
        if (t0 < 6) LOAD(va, t0 + 2);
        COMPUTE(As0, t0);
        __syncthreads();
        if (t0 + 2 < 8) STAGE(va, As0);      // stage step t0+2
        if (t0 + 3 < 8) LOAD(vb, t0 + 3);
        COMPUTE(As1, t0 + 1);
        __syncthreads();
    }

#pragma unroll
    for (int mi = 0; mi < 4; ++mi)
#pragma unroll
        for (int ni = 0; ni < 4; ++ni) {
            const int row = s0 + mrow0 + mi * 16 + lq * 4;
            const int col = n0 + ncol0 + ni * 16 + lc;
            const float cv = corr[ncol0 + ni * 16 + lc];
#pragma unroll
            for (int r = 0; r < 4; ++r)
                ob[(size_t)(row + r) * DD + col] = acc[mi][ni][r] - cv;
        }
}

extern "C" void kernel_launch(void* const* d_in, const int* in_sizes, int n_in,
                              void* d_out, int out_size, void* d_ws, size_t ws_size,
                              hipStream_t stream) {
    const float* x = (const float*)d_in[0];
    float* out = (float*)d_out;
    float* ws = (float*)d_ws;

    const size_t MAT = (size_t)BB * DD * DD;        // 1,048,576 floats
    float* partial = ws;                            // 8 * MAT = 32 MB
    float* sumx8 = partial + 8 * MAT;               // 8*16*256 = 32768
    float* m     = sumx8 + 8 * BB * DD;             // 4096
    float* trbuf = m + BB * DD;                     // 64
    float* Xa    = trbuf + 64;
    float* Xb    = Xa + MAT;
    float* T     = Xb + MAT;
    float* Pa    = T + MAT;
    float* Pb    = Pa + MAT;

    moment_kernel<<<dim3(8, 2, 16), 512, 0, stream>>>(x, partial, sumx8);
    stats_kernel<<<16, 256, 0, stream>>>(partial, sumx8, m, trbuf);
    sigman_kernel<<<dim3(256, 16), 256, 0, stream>>>(partial, m, trbuf, Xa);

    // Newton-Schulz: X_{k+1} = X_k W_k^2, P_{k+1} = P_k W_k, W_k = 1.5I - 0.5 X_k
    // (all symmetric, commuting). Independent products fused 2-per-launch.
    bmm_mfma<<<dim3(16, 16), 256, 0, stream>>>(Xa, Xa, T, 1, 1,
                                               Xa, Xa, T, 1, 1);   // T  = W0^2
    bmm_mfma<<<dim3(16, 16), 256, 0, stream>>>(Xa, T, Xb, 0, 0,
                                               Xa, T, Xb, 0, 0);   // X1 = X0*T
    bmm_mfma<<<dim3(16, 32), 256, 0, stream>>>(Xa, Xb, Pa, 1, 1,   // P2 = W0*W1
                                               Xb, Xb, T, 1, 1);   // T  = W1^2
    bmm_mfma<<<dim3(16, 16), 256, 0, stream>>>(Xb, T, Xa, 0, 0,
                                               Xb, T, Xa, 0, 0);   // X2 = X1*T
    bmm_mfma<<<dim3(16, 32), 256, 0, stream>>>(Pa, Xa, Pb, 0, 1,   // P3 = P2*W2
                                               Xa, Xa, T, 1, 1);   // T  = W2^2
    bmm_mfma<<<dim3(16, 16), 256, 0, stream>>>(Xa, T, Xb, 0, 0,
                                               Xa, T, Xb, 0, 0);   // X3 = X2*T
    bmm_mfma<<<dim3(16, 16), 256, 0, stream>>>(Pb, Xb, Pa, 0, 1,
                                               Pb, Xb, Pa, 0, 1);  // P4 = P3*W3

    apply_kernel<<<dim3(32, 2, 16), 512, 0, stream>>>(x, Pa, m, trbuf, out);
}